// Round 6
// baseline (370.799 us; speedup 1.0000x reference)
//
#include <hip/hip_runtime.h>
#include <hip/hip_bf16.h>

// Problem constants (BS=1)
#define CAMS   6
#define NQ     6400
#define EMBED  256
#define HEADS  8
#define LEVELS 4
#define POINTS 8
#define DEPTH  4
#define DH     32
#define FLEN   14960
#define MV     (FLEN * CAMS)   // 89760 rows for v-projection
#define NCHUNK 2805            // MV / 32
#define NQCHUNK 200            // NQ / 32

__constant__ int c_LW[4] = {176, 88, 44, 22};
__constant__ int c_LH[4] = {64, 32, 16, 8};
__constant__ int c_LS[4] = {0, 11264, 14080, 14784};

typedef __bf16 bf16x8 __attribute__((ext_vector_type(8)));
typedef float  f32x4  __attribute__((ext_vector_type(4)));

__device__ __forceinline__ ushort f2bf(float x) {
    __hip_bfloat16 h = __float2bfloat16(x);
    return *(ushort*)&h;
}
__device__ __forceinline__ float bflo(unsigned u) { return __uint_as_float(u << 16); }
__device__ __forceinline__ float bfhi(unsigned u) { return __uint_as_float(u & 0xffff0000u); }

__device__ __forceinline__ bf16x8 pack8(float4 a, float4 b) {
    union { ushort u[8]; bf16x8 v; } r;
    r.u[0] = f2bf(a.x); r.u[1] = f2bf(a.y); r.u[2] = f2bf(a.z); r.u[3] = f2bf(a.w);
    r.u[4] = f2bf(b.x); r.u[5] = f2bf(b.y); r.u[6] = f2bf(b.z); r.u[7] = f2bf(b.w);
    return r.v;
}

#define LSTRIDE 40

// ---------------------------------------------------------------------------
// Out-projection GEMM (verified R3/R4): C = A@W + b + resid, fp32 out.
// ---------------------------------------------------------------------------
__device__ __forceinline__ void gemm_body_out(ushort* sA, ushort* sB,
                                              const float* __restrict__ A,
                                              const float* __restrict__ W, int ldw,
                                              const float* __restrict__ bias,
                                              const float* __restrict__ resid,
                                              float* __restrict__ Cout, int ldc, int M,
                                              int bx, int by) {
    const int t = threadIdx.x;
    const int wave = t >> 6;
    const int lane = t & 63;
    const int wm = wave & 1, wn = wave >> 1;
    const int lane15 = lane & 15;
    const int laneq = lane >> 4;
    const int row0 = bx * 128;
    const int col0 = by * 128;

    f32x4 acc[4][4] = {};

    const int a_m = t >> 3;
    const int a_k = (t & 7) * 4;
    const int b_n = t & 127;
    const int b_k = (t >> 7) * 4;

    float4 aR[4], wR[4];

    #pragma unroll
    for (int p = 0; p < 4; ++p) {
        int gm = row0 + a_m + p * 32;
        if (gm >= M) gm = M - 1;
        aR[p] = *(const float4*)(A + (size_t)gm * 256 + a_k);
    }
    #pragma unroll
    for (int p = 0; p < 4; ++p) {
        const int k = b_k + p * 8;
        const float* wp = W + (size_t)k * ldw + col0 + b_n;
        wR[p] = make_float4(wp[0], wp[ldw], wp[2 * ldw], wp[3 * ldw]);
    }

    for (int k0 = 0; k0 < 256; k0 += 32) {
        #pragma unroll
        for (int p = 0; p < 4; ++p) {
            const int m = a_m + p * 32;
            const float4 a4 = aR[p];
            *(ushort4*)(&sA[m * LSTRIDE + a_k]) =
                make_ushort4(f2bf(a4.x), f2bf(a4.y), f2bf(a4.z), f2bf(a4.w));
        }
        #pragma unroll
        for (int p = 0; p < 4; ++p) {
            const int k = b_k + p * 8;
            *(ushort4*)(&sB[b_n * LSTRIDE + k]) =
                make_ushort4(f2bf(wR[p].x), f2bf(wR[p].y), f2bf(wR[p].z), f2bf(wR[p].w));
        }
        __syncthreads();

        if (k0 + 32 < 256) {
            #pragma unroll
            for (int p = 0; p < 4; ++p) {
                int gm = row0 + a_m + p * 32;
                if (gm >= M) gm = M - 1;
                aR[p] = *(const float4*)(A + (size_t)gm * 256 + k0 + 32 + a_k);
            }
            #pragma unroll
            for (int p = 0; p < 4; ++p) {
                const int k = b_k + p * 8;
                const float* wp = W + (size_t)(k0 + 32 + k) * ldw + col0 + b_n;
                wR[p] = make_float4(wp[0], wp[ldw], wp[2 * ldw], wp[3 * ldw]);
            }
        }

        bf16x8 af[4], bfr[4];
        #pragma unroll
        for (int i = 0; i < 4; ++i) {
            const int m = wm * 64 + i * 16 + lane15;
            af[i] = *(const bf16x8*)(&sA[m * LSTRIDE + laneq * 8]);
            const int n = wn * 64 + i * 16 + lane15;
            bfr[i] = *(const bf16x8*)(&sB[n * LSTRIDE + laneq * 8]);
        }
        #pragma unroll
        for (int i = 0; i < 4; ++i)
            #pragma unroll
            for (int j = 0; j < 4; ++j)
                acc[i][j] = __builtin_amdgcn_mfma_f32_16x16x32_bf16(af[i], bfr[j], acc[i][j], 0, 0, 0);
        __syncthreads();
    }

    #pragma unroll
    for (int j = 0; j < 4; ++j) {
        const int col = col0 + wn * 64 + j * 16 + lane15;
        const float bcol = bias[col];
        #pragma unroll
        for (int i = 0; i < 4; ++i) {
            #pragma unroll
            for (int r = 0; r < 4; ++r) {
                const int row = row0 + wm * 64 + i * 16 + laneq * 4 + r;
                if (row < M) {
                    float v = acc[i][j][r] + bcol + resid[(size_t)row * 256 + col];
                    Cout[(size_t)row * ldc + col] = v;
                }
            }
        }
    }
}

__device__ __forceinline__ void add4(float4& a, float4 b) {
    a.x += b.x; a.y += b.y; a.z += b.z; a.w += b.w;
}

// ---------------------------------------------------------------------------
// W-stationary barrier-free projection (verified structure from R4's v-proj).
// Stages a 256(K)x256(N) bf16 W-slice (128 KiB) to LDS once (XOR swizzle
// k^((n&7)<<3) for conflict-minimal ds_read_b128), then each wave streams
// 32-row chunks of A independently: preload whole chunk's A to regs,
// 256 MFMA, store. No barriers in the loop.
// QMODE 0: A @ W + b -> bf16 scatter to v_ws[cam][head][pix][32ch]
// QMODE 1: (A+A2) @ W[:, c0:c0+256] + b -> fp32 linear out
// ---------------------------------------------------------------------------
template <int QMODE>
__device__ __forceinline__ void wstat_body(ushort* sW,
                                           const float* __restrict__ A,
                                           const float* __restrict__ A2,
                                           const float* __restrict__ W, int ldw, int c0,
                                           const float* __restrict__ bias,
                                           void* __restrict__ out, int ldc,
                                           int nchunk, int blk, int nblk) {
    const int t = threadIdx.x;

    // ---- stage W slice: thread t owns local column n=t
    {
        const int n = t;
        const int xr = (n & 7) << 3;
        #pragma unroll 8
        for (int r = 0; r < 64; ++r) {
            const int k4 = r * 4;
            const float w0 = W[(size_t)(k4 + 0) * ldw + c0 + n];
            const float w1 = W[(size_t)(k4 + 1) * ldw + c0 + n];
            const float w2 = W[(size_t)(k4 + 2) * ldw + c0 + n];
            const float w3 = W[(size_t)(k4 + 3) * ldw + c0 + n];
            *(ushort4*)(&sW[n * 256 + (k4 ^ xr)]) =
                make_ushort4(f2bf(w0), f2bf(w1), f2bf(w2), f2bf(w3));
        }
    }
    __syncthreads();

    const int wave = t >> 6, lane = t & 63;
    const int lane15 = lane & 15, laneq = lane >> 4;

    float bcol[16];
    #pragma unroll
    for (int nt = 0; nt < 16; ++nt) bcol[nt] = bias[c0 + nt * 16 + lane15];

    for (int c = blk * 4 + wave; c < nchunk; c += nblk * 4) {
        const int rowbase = c * 32;
        const float* ap0 = A + (size_t)(rowbase + lane15) * 256 + laneq * 8;
        const float* ap1 = ap0 + 16 * 256;

        float4 a[2][8][2];
        #pragma unroll
        for (int s = 0; s < 8; ++s) {
            a[0][s][0] = *(const float4*)(ap0 + s * 32);
            a[0][s][1] = *(const float4*)(ap0 + s * 32 + 4);
            a[1][s][0] = *(const float4*)(ap1 + s * 32);
            a[1][s][1] = *(const float4*)(ap1 + s * 32 + 4);
        }
        if (QMODE == 1) {
            const float* bp0 = A2 + (size_t)(rowbase + lane15) * 256 + laneq * 8;
            const float* bp1 = bp0 + 16 * 256;
            #pragma unroll
            for (int s = 0; s < 8; ++s) {
                add4(a[0][s][0], *(const float4*)(bp0 + s * 32));
                add4(a[0][s][1], *(const float4*)(bp0 + s * 32 + 4));
                add4(a[1][s][0], *(const float4*)(bp1 + s * 32));
                add4(a[1][s][1], *(const float4*)(bp1 + s * 32 + 4));
            }
        }

        f32x4 acc[2][16] = {};
        #pragma unroll
        for (int s = 0; s < 8; ++s) {
            const bf16x8 fa0 = pack8(a[0][s][0], a[0][s][1]);
            const bf16x8 fa1 = pack8(a[1][s][0], a[1][s][1]);
            const int kb = laneq * 8 + s * 32;
            #pragma unroll
            for (int nt = 0; nt < 16; ++nt) {
                const int n = nt * 16 + lane15;
                const bf16x8 fb = *(const bf16x8*)(&sW[n * 256 + (kb ^ ((n & 7) << 3))]);
                acc[0][nt] = __builtin_amdgcn_mfma_f32_16x16x32_bf16(fa0, fb, acc[0][nt], 0, 0, 0);
                acc[1][nt] = __builtin_amdgcn_mfma_f32_16x16x32_bf16(fa1, fb, acc[1][nt], 0, 0, 0);
            }
        }

        #pragma unroll
        for (int rt = 0; rt < 2; ++rt) {
            #pragma unroll
            for (int r = 0; r < 4; ++r) {
                const int row = rowbase + rt * 16 + laneq * 4 + r;
                if (QMODE == 0) {
                    const unsigned pix = ((unsigned)row * 43691u) >> 18;   // row/6
                    const unsigned cam = (unsigned)row - pix * 6u;
                    const unsigned base = (cam * 8u * FLEN + pix) * 32u;
                    #pragma unroll
                    for (int nt = 0; nt < 16; ++nt) {
                        const unsigned idx = base + (unsigned)(nt >> 1) * (FLEN * 32u)
                                           + (unsigned)((nt & 1) * 16 + lane15);
                        ((ushort*)out)[idx] = f2bf(acc[rt][nt][r] + bcol[nt]);
                    }
                } else {
                    float* op = (float*)out + (size_t)row * ldc + c0 + lane15;
                    #pragma unroll
                    for (int nt = 0; nt < 16; ++nt)
                        op[nt * 16] = acc[rt][nt][r] + bcol[nt];
                }
            }
        }
    }
}

// ---------------------------------------------------------------------------
// One launch, one round of 256 W-stationary blocks (1/CU, 128 KiB LDS each),
// partitioned by work (≈3.3 chunks/wave each):
//   blocks [0,211)    : v-proj   (2805 chunks) -> v_ws bf16 scatter
//   blocks [211,226)  : (q+pos) @ Wso[:,0:256]   -> off_ws cols 0..255
//   blocks [226,241)  : (q+pos) @ Wso[:,256:512] -> off_ws cols 256..511
//   blocks [241,256)  : (q+pos) @ Waw            -> aw_ws (raw logits)
//   block  256        : bev_mask format detect -> flag (tiny tail)
// ---------------------------------------------------------------------------
__launch_bounds__(256, 1)
__global__ void fused_pre_gemm(const float* __restrict__ value,
                               const float* __restrict__ query,
                               const float* __restrict__ query_pos,
                               const float* __restrict__ Wv,  const float* __restrict__ bv,
                               const float* __restrict__ Wso, const float* __restrict__ bso,
                               const float* __restrict__ Waw, const float* __restrict__ baw,
                               const void* __restrict__ bm,
                               ushort* __restrict__ v_ws,
                               float* __restrict__ off_ws,
                               float* __restrict__ aw_ws,
                               int* __restrict__ flag) {
    __shared__ ushort sW[256 * 256];   // 128 KiB
    const int bid = blockIdx.x;
    if (bid < 211) {
        wstat_body<0>(sW, value, nullptr, Wv, 256, 0, bv, v_ws, 0, NCHUNK, bid, 211);
    } else if (bid < 226) {
        wstat_body<1>(sW, query, query_pos, Wso, 512, 0,   bso, off_ws, 512, NQCHUNK, bid - 211, 15);
    } else if (bid < 241) {
        wstat_body<1>(sW, query, query_pos, Wso, 512, 256, bso, off_ws, 512, NQCHUNK, bid - 226, 15);
    } else if (bid < 256) {
        wstat_body<1>(sW, query, query_pos, Waw, 256, 0,   baw, aw_ws, 256, NQCHUNK, bid - 241, 15);
    } else {
        // scan first 153600 B of bev_mask: bool-byte packing sets upper bytes
        // of 32-bit words; int32 0/1 values never do.
        const int t = threadIdx.x;
        const uint4* p4 = (const uint4*)bm;
        unsigned acc = 0;
        for (int i = t; i < (CAMS * NQ * DEPTH) / 16; i += 256) {
            const uint4 w = p4[i];
            acc |= w.x | w.y | w.z | w.w;
        }
        #pragma unroll
        for (int off = 32; off >= 1; off >>= 1) acc |= __shfl_xor(acc, off);
        unsigned* sred = (unsigned*)sW;
        if ((t & 63) == 0) sred[t >> 6] = acc;
        __syncthreads();
        if (t == 0) {
            const unsigned a = sred[0] | sred[1] | sred[2] | sred[3];
            flag[0] = (a & 0xFFFFFF00u) ? 1 : 0;
        }
    }
}

__launch_bounds__(256)
__global__ void gemm_out_kernel(const float* __restrict__ slots,
                                const float* __restrict__ Wout,
                                const float* __restrict__ bout,
                                const float* __restrict__ query,
                                float* __restrict__ out) {
    __shared__ ushort sA[128 * LSTRIDE];
    __shared__ ushort sB[128 * LSTRIDE];
    const int bid = blockIdx.x;
    gemm_body_out(sA, sB, slots, Wout, 256, bout, query, out, 256, NQ, bid >> 1, bid & 1);
}

// ---------------------------------------------------------------------------
// Deformable sampling — mask decode, softmax, 1/count folded in.
// v layout is [cam][head][pix][32ch] bf16. One block per query; thread
// t = h*32 + e8*4 + ch8idx handles entries e8*4+j (j=depth), channels ch8..+7.
// Cam loop is software-pipelined 2-deep (A/B register buffers): stage cam
// i+1's rp->addr->16 gathers BEFORE consuming cam i's FMAs, walking the
// active-cam bitmask with __ffs. Accumulation order identical to serial.
// ---------------------------------------------------------------------------
#define STAGE(ADDR, WGT, UU, CAM) do {                                          \
    const int cam_ = (CAM);                                                     \
    const float4 r01_ = *(const float4*)(rp + (size_t)cam_ * (NQ * 8) + q * 8); \
    const float4 r23_ = *(const float4*)(rp + (size_t)cam_ * (NQ * 8) + q * 8 + 4); \
    const float rx_[4] = {r01_.x, r01_.z, r23_.x, r23_.z};                      \
    const float ry_[4] = {r01_.y, r01_.w, r23_.y, r23_.w};                      \
    const int camhF_ = (cam_ * 8 + h) * FLEN + St;                              \
    _Pragma("unroll")                                                           \
    for (int j = 0; j < 4; ++j) {                                               \
        const float x = fmaf(rx_[j], fWl, offx[j]) - 0.5f;                      \
        const float y = fmaf(ry_[j], fHl, offy[j]) - 0.5f;                      \
        const float x0f = floorf(x), y0f = floorf(y);                           \
        const int x0 = (int)x0f, y0 = (int)y0f;                                 \
        const float fx = x - x0f, fy = y - y0f;                                 \
        const float wx0 = 1.f - fx, wy0 = 1.f - fy;                             \
        _Pragma("unroll")                                                       \
        for (int cc = 0; cc < 4; ++cc) {                                        \
            const int cx = x0 + (cc & 1);                                       \
            const int cy = y0 + (cc >> 1);                                      \
            const bool valid = ((unsigned)cx < (unsigned)Wl) & ((unsigned)cy < (unsigned)Hl); \
            const int pixo = valid ? (cy * Wl + cx) : 0;                        \
            ADDR[j * 4 + cc] = ((camhF_ + pixo) << 5) + ch8;                    \
            WGT[j * 4 + cc] = valid                                             \
                ? (((cc & 1) ? fx : wx0) * ((cc >> 1) ? fy : wy0) * awv[j])     \
                : 0.f;                                                          \
        }                                                                       \
    }                                                                           \
    _Pragma("unroll")                                                           \
    for (int i = 0; i < 16; ++i) UU[i] = *(const uint4*)(v + ADDR[i]);          \
} while (0)

#define CONSUME(UU, WGT) do {                                                   \
    _Pragma("unroll")                                                           \
    for (int i = 0; i < 16; ++i) {                                              \
        const uint4 u = UU[i];                                                  \
        const float w = WGT[i];                                                 \
        accv[0] = fmaf(w, bflo(u.x), accv[0]);                                  \
        accv[1] = fmaf(w, bfhi(u.x), accv[1]);                                  \
        accv[2] = fmaf(w, bflo(u.y), accv[2]);                                  \
        accv[3] = fmaf(w, bfhi(u.y), accv[3]);                                  \
        accv[4] = fmaf(w, bflo(u.z), accv[4]);                                  \
        accv[5] = fmaf(w, bfhi(u.z), accv[5]);                                  \
        accv[6] = fmaf(w, bflo(u.w), accv[6]);                                  \
        accv[7] = fmaf(w, bfhi(u.w), accv[7]);                                  \
    }                                                                           \
} while (0)

__launch_bounds__(256)
__global__ void sample_kernel(const ushort* __restrict__ v,
                              const float* __restrict__ off_ws,
                              const float* __restrict__ aw_logit,
                              const float* __restrict__ rp,      // (CAMS,NQ,DEPTH,2)
                              const void* __restrict__ bm,
                              const int* __restrict__ flag,
                              float* __restrict__ slots) {
    const int q = blockIdx.x;
    const int t = threadIdx.x;
    const int h = t >> 5;
    const int e8 = (t >> 2) & 7;
    const int ch8 = (t & 3) * 8;
    const int l = e8 >> 1;
    const int ebase = h * 32 + e8 * 4;

    const int Wl = c_LW[l], Hl = c_LH[l], St = c_LS[l];
    const float fWl = (float)Wl, fHl = (float)Hl;

    const int fmt = *flag;
    int am = 0, cnt = 0;
    if (fmt == 1) {         // bool bytes: 4 bytes per (cam,q)
        #pragma unroll
        for (int cam = 0; cam < CAMS; ++cam) {
            const unsigned w = ((const unsigned*)bm)[cam * NQ + q];
            const int a = (w != 0u);
            am |= a << cam;
            cnt += a;
        }
    } else {                // int32: 16 bytes per (cam,q)
        #pragma unroll
        for (int cam = 0; cam < CAMS; ++cam) {
            const int4 w = ((const int4*)bm)[cam * NQ + q];
            const int a = ((w.x | w.y | w.z | w.w) != 0);
            am |= a << cam;
            cnt += a;
        }
    }
    const float invq = 1.0f / (float)(cnt > 0 ? cnt : 1);

    // softmax over the 32 (l,p) logits of this (q,h): lanes differing in e8
    const float4 lg = *(const float4*)(aw_logit + (size_t)q * 256 + ebase);
    float mx = fmaxf(fmaxf(lg.x, lg.y), fmaxf(lg.z, lg.w));
    mx = fmaxf(mx, __shfl_xor(mx, 4));
    mx = fmaxf(mx, __shfl_xor(mx, 8));
    mx = fmaxf(mx, __shfl_xor(mx, 16));
    const float e0 = expf(lg.x - mx), e1 = expf(lg.y - mx);
    const float e2 = expf(lg.z - mx), e3 = expf(lg.w - mx);
    float s = e0 + e1 + e2 + e3;
    s += __shfl_xor(s, 4);
    s += __shfl_xor(s, 8);
    s += __shfl_xor(s, 16);
    const float sc = invq / s;                 // fold 1/count into the weights
    const float awv[4] = {e0 * sc, e1 * sc, e2 * sc, e3 * sc};

    const float* ofp = off_ws + (size_t)q * 512 + ebase * 2;
    const float4 o01 = *(const float4*)(ofp);
    const float4 o23 = *(const float4*)(ofp + 4);
    const float offx[4] = {o01.x, o01.z, o23.x, o23.z};
    const float offy[4] = {o01.y, o01.w, o23.y, o23.w};

    float accv[8] = {};

    // ---- 2-deep software pipeline over active cams (ascending order) ----
    int   addrA[16], addrB[16];
    float wgtA[16], wgtB[16];
    uint4 uA[16], uB[16];

    int m = am;
    int camA = -1;
    if (m) { camA = __ffs(m) - 1; m &= m - 1; STAGE(addrA, wgtA, uA, camA); }

    #pragma unroll
    for (int it = 0; it < 3; ++it) {
        if (camA < 0) break;
        int camB = -1;
        if (m) { camB = __ffs(m) - 1; m &= m - 1; STAGE(addrB, wgtB, uB, camB); }
        CONSUME(uA, wgtA);
        camA = -1;
        if (camB < 0) break;
        if (m) { camA = __ffs(m) - 1; m &= m - 1; STAGE(addrA, wgtA, uA, camA); }
        CONSUME(uB, wgtB);
    }

    // reduce over the 8 e8-groups (lane bits 2..4 within each 32-lane h-group)
    #pragma unroll
    for (int i = 0; i < 8; ++i) {
        accv[i] += __shfl_xor(accv[i], 4);
        accv[i] += __shfl_xor(accv[i], 8);
        accv[i] += __shfl_xor(accv[i], 16);
    }
    slots[(size_t)q * 256 + h * 32 + ch8 + e8] = accv[e8];
}

// ---------------------------------------------------------------------------
extern "C" void kernel_launch(void* const* d_in, const int* in_sizes, int n_in,
                              void* d_out, int out_size, void* d_ws, size_t ws_size,
                              hipStream_t stream) {
    const float* query     = (const float*)d_in[0];
    // d_in[1] = key (unused by reference)
    const float* value     = (const float*)d_in[2];
    const float* query_pos = (const float*)d_in[3];
    const float* refpts    = (const float*)d_in[4];
    const void*  bev_mask  = d_in[5];
    const float* Wv   = (const float*)d_in[8];
    const float* bv   = (const float*)d_in[9];
    const float* Wso  = (const float*)d_in[10];
    const float* bso  = (const float*)d_in[11];
    const float* Waw  = (const float*)d_in[12];
    const float* baw  = (const float*)d_in[13];
    const float* Wout = (const float*)d_in[14];
    const float* bout = (const float*)d_in[15];
    float* out = (float*)d_out;

    // Workspace layout
    ushort* v_ws  = (ushort*)d_ws;                       // MV*256 bf16 = 45.96 MB
    float* off_ws = (float*)(v_ws + (size_t)MV * 256);   // NQ*512 fp32
    float* aw_ws  = off_ws + (size_t)NQ * 512;           // NQ*256 (raw logits)
    float* slots  = aw_ws + (size_t)NQ * 256;            // NQ*256
    int*   flag   = (int*)(slots + (size_t)NQ * 256);    // 1 int

    // all projections (W-stationary, one round) + mask detect, one dispatch
    hipLaunchKernelGGL(fused_pre_gemm, dim3(257), dim3(256), 0, stream,
                       value, query, query_pos, Wv, bv, Wso, bso, Waw, baw,
                       bev_mask, v_ws, off_ws, aw_ws, flag);

    // deformable sampling (mask decode + softmax + 1/count folded in)
    hipLaunchKernelGGL(sample_kernel, dim3(NQ), dim3(256), 0, stream,
                       v_ws, off_ws, aw_ws, refpts, bev_mask, flag, slots);

    // out = slots @ Wout + bout + query   (1/count already folded into sample)
    hipLaunchKernelGGL(gemm_out_kernel, dim3(100), dim3(256), 0, stream,
                       slots, Wout, bout, query, out);
}

// Round 7
// 370.201 us; speedup vs baseline: 1.0016x; 1.0016x over previous
//
#include <hip/hip_runtime.h>
#include <hip/hip_bf16.h>

// Problem constants (BS=1)
#define CAMS   6
#define NQ     6400
#define EMBED  256
#define HEADS  8
#define LEVELS 4
#define POINTS 8
#define DEPTH  4
#define DH     32
#define FLEN   14960
#define MV     (FLEN * CAMS)   // 89760 rows for v-projection
#define NCHUNK 2805            // MV / 32
#define NQCHUNK 200            // NQ / 32

__constant__ int c_LW[4] = {176, 88, 44, 22};
__constant__ int c_LH[4] = {64, 32, 16, 8};
__constant__ int c_LS[4] = {0, 11264, 14080, 14784};

typedef __bf16 bf16x8 __attribute__((ext_vector_type(8)));
typedef float  f32x4  __attribute__((ext_vector_type(4)));

__device__ __forceinline__ ushort f2bf(float x) {
    __hip_bfloat16 h = __float2bfloat16(x);
    return *(ushort*)&h;
}
__device__ __forceinline__ float bflo(unsigned u) { return __uint_as_float(u << 16); }
__device__ __forceinline__ float bfhi(unsigned u) { return __uint_as_float(u & 0xffff0000u); }

__device__ __forceinline__ bf16x8 pack8(float4 a, float4 b) {
    union { ushort u[8]; bf16x8 v; } r;
    r.u[0] = f2bf(a.x); r.u[1] = f2bf(a.y); r.u[2] = f2bf(a.z); r.u[3] = f2bf(a.w);
    r.u[4] = f2bf(b.x); r.u[5] = f2bf(b.y); r.u[6] = f2bf(b.z); r.u[7] = f2bf(b.w);
    return r.v;
}

#define LSTRIDE 40

// ---------------------------------------------------------------------------
// Out-projection GEMM (verified R3/R4): C = A@W + b + resid, fp32 out.
// ---------------------------------------------------------------------------
__device__ __forceinline__ void gemm_body_out(ushort* sA, ushort* sB,
                                              const float* __restrict__ A,
                                              const float* __restrict__ W, int ldw,
                                              const float* __restrict__ bias,
                                              const float* __restrict__ resid,
                                              float* __restrict__ Cout, int ldc, int M,
                                              int bx, int by) {
    const int t = threadIdx.x;
    const int wave = t >> 6;
    const int lane = t & 63;
    const int wm = wave & 1, wn = wave >> 1;
    const int lane15 = lane & 15;
    const int laneq = lane >> 4;
    const int row0 = bx * 128;
    const int col0 = by * 128;

    f32x4 acc[4][4] = {};

    const int a_m = t >> 3;
    const int a_k = (t & 7) * 4;
    const int b_n = t & 127;
    const int b_k = (t >> 7) * 4;

    float4 aR[4], wR[4];

    #pragma unroll
    for (int p = 0; p < 4; ++p) {
        int gm = row0 + a_m + p * 32;
        if (gm >= M) gm = M - 1;
        aR[p] = *(const float4*)(A + (size_t)gm * 256 + a_k);
    }
    #pragma unroll
    for (int p = 0; p < 4; ++p) {
        const int k = b_k + p * 8;
        const float* wp = W + (size_t)k * ldw + col0 + b_n;
        wR[p] = make_float4(wp[0], wp[ldw], wp[2 * ldw], wp[3 * ldw]);
    }

    for (int k0 = 0; k0 < 256; k0 += 32) {
        #pragma unroll
        for (int p = 0; p < 4; ++p) {
            const int m = a_m + p * 32;
            const float4 a4 = aR[p];
            *(ushort4*)(&sA[m * LSTRIDE + a_k]) =
                make_ushort4(f2bf(a4.x), f2bf(a4.y), f2bf(a4.z), f2bf(a4.w));
        }
        #pragma unroll
        for (int p = 0; p < 4; ++p) {
            const int k = b_k + p * 8;
            *(ushort4*)(&sB[b_n * LSTRIDE + k]) =
                make_ushort4(f2bf(wR[p].x), f2bf(wR[p].y), f2bf(wR[p].z), f2bf(wR[p].w));
        }
        __syncthreads();

        if (k0 + 32 < 256) {
            #pragma unroll
            for (int p = 0; p < 4; ++p) {
                int gm = row0 + a_m + p * 32;
                if (gm >= M) gm = M - 1;
                aR[p] = *(const float4*)(A + (size_t)gm * 256 + k0 + 32 + a_k);
            }
            #pragma unroll
            for (int p = 0; p < 4; ++p) {
                const int k = b_k + p * 8;
                const float* wp = W + (size_t)(k0 + 32 + k) * ldw + col0 + b_n;
                wR[p] = make_float4(wp[0], wp[ldw], wp[2 * ldw], wp[3 * ldw]);
            }
        }

        bf16x8 af[4], bfr[4];
        #pragma unroll
        for (int i = 0; i < 4; ++i) {
            const int m = wm * 64 + i * 16 + lane15;
            af[i] = *(const bf16x8*)(&sA[m * LSTRIDE + laneq * 8]);
            const int n = wn * 64 + i * 16 + lane15;
            bfr[i] = *(const bf16x8*)(&sB[n * LSTRIDE + laneq * 8]);
        }
        #pragma unroll
        for (int i = 0; i < 4; ++i)
            #pragma unroll
            for (int j = 0; j < 4; ++j)
                acc[i][j] = __builtin_amdgcn_mfma_f32_16x16x32_bf16(af[i], bfr[j], acc[i][j], 0, 0, 0);
        __syncthreads();
    }

    #pragma unroll
    for (int j = 0; j < 4; ++j) {
        const int col = col0 + wn * 64 + j * 16 + lane15;
        const float bcol = bias[col];
        #pragma unroll
        for (int i = 0; i < 4; ++i) {
            #pragma unroll
            for (int r = 0; r < 4; ++r) {
                const int row = row0 + wm * 64 + i * 16 + laneq * 4 + r;
                if (row < M) {
                    float v = acc[i][j][r] + bcol + resid[(size_t)row * 256 + col];
                    Cout[(size_t)row * ldc + col] = v;
                }
            }
        }
    }
}

__device__ __forceinline__ void add4(float4& a, float4 b) {
    a.x += b.x; a.y += b.y; a.z += b.z; a.w += b.w;
}

// ---------------------------------------------------------------------------
// W-stationary barrier-free projection (verified R6).
// Stages a 256(K)x256(N) bf16 W-slice (128 KiB) to LDS once (XOR swizzle
// k^((n&7)<<3) for conflict-minimal ds_read_b128), then each wave streams
// 32-row chunks of A independently. No barriers in the loop.
// QMODE 0: A @ W + b -> bf16 scatter to v_ws[cam][head][pix][32ch]
// QMODE 1: (A+A2) @ W[:, c0:c0+256] + b -> fp32 linear out
// ---------------------------------------------------------------------------
template <int QMODE>
__device__ __forceinline__ void wstat_body(ushort* sW,
                                           const float* __restrict__ A,
                                           const float* __restrict__ A2,
                                           const float* __restrict__ W, int ldw, int c0,
                                           const float* __restrict__ bias,
                                           void* __restrict__ out, int ldc,
                                           int nchunk, int blk, int nblk) {
    const int t = threadIdx.x;

    // ---- stage W slice: thread t owns local column n=t
    {
        const int n = t;
        const int xr = (n & 7) << 3;
        #pragma unroll 8
        for (int r = 0; r < 64; ++r) {
            const int k4 = r * 4;
            const float w0 = W[(size_t)(k4 + 0) * ldw + c0 + n];
            const float w1 = W[(size_t)(k4 + 1) * ldw + c0 + n];
            const float w2 = W[(size_t)(k4 + 2) * ldw + c0 + n];
            const float w3 = W[(size_t)(k4 + 3) * ldw + c0 + n];
            *(ushort4*)(&sW[n * 256 + (k4 ^ xr)]) =
                make_ushort4(f2bf(w0), f2bf(w1), f2bf(w2), f2bf(w3));
        }
    }
    __syncthreads();

    const int wave = t >> 6, lane = t & 63;
    const int lane15 = lane & 15, laneq = lane >> 4;

    float bcol[16];
    #pragma unroll
    for (int nt = 0; nt < 16; ++nt) bcol[nt] = bias[c0 + nt * 16 + lane15];

    for (int c = blk * 4 + wave; c < nchunk; c += nblk * 4) {
        const int rowbase = c * 32;
        const float* ap0 = A + (size_t)(rowbase + lane15) * 256 + laneq * 8;
        const float* ap1 = ap0 + 16 * 256;

        float4 a[2][8][2];
        #pragma unroll
        for (int s = 0; s < 8; ++s) {
            a[0][s][0] = *(const float4*)(ap0 + s * 32);
            a[0][s][1] = *(const float4*)(ap0 + s * 32 + 4);
            a[1][s][0] = *(const float4*)(ap1 + s * 32);
            a[1][s][1] = *(const float4*)(ap1 + s * 32 + 4);
        }
        if (QMODE == 1) {
            const float* bp0 = A2 + (size_t)(rowbase + lane15) * 256 + laneq * 8;
            const float* bp1 = bp0 + 16 * 256;
            #pragma unroll
            for (int s = 0; s < 8; ++s) {
                add4(a[0][s][0], *(const float4*)(bp0 + s * 32));
                add4(a[0][s][1], *(const float4*)(bp0 + s * 32 + 4));
                add4(a[1][s][0], *(const float4*)(bp1 + s * 32));
                add4(a[1][s][1], *(const float4*)(bp1 + s * 32 + 4));
            }
        }

        f32x4 acc[2][16] = {};
        #pragma unroll
        for (int s = 0; s < 8; ++s) {
            const bf16x8 fa0 = pack8(a[0][s][0], a[0][s][1]);
            const bf16x8 fa1 = pack8(a[1][s][0], a[1][s][1]);
            const int kb = laneq * 8 + s * 32;
            #pragma unroll
            for (int nt = 0; nt < 16; ++nt) {
                const int n = nt * 16 + lane15;
                const bf16x8 fb = *(const bf16x8*)(&sW[n * 256 + (kb ^ ((n & 7) << 3))]);
                acc[0][nt] = __builtin_amdgcn_mfma_f32_16x16x32_bf16(fa0, fb, acc[0][nt], 0, 0, 0);
                acc[1][nt] = __builtin_amdgcn_mfma_f32_16x16x32_bf16(fa1, fb, acc[1][nt], 0, 0, 0);
            }
        }

        #pragma unroll
        for (int rt = 0; rt < 2; ++rt) {
            #pragma unroll
            for (int r = 0; r < 4; ++r) {
                const int row = rowbase + rt * 16 + laneq * 4 + r;
                if (QMODE == 0) {
                    const unsigned pix = ((unsigned)row * 43691u) >> 18;   // row/6
                    const unsigned cam = (unsigned)row - pix * 6u;
                    const unsigned base = (cam * 8u * FLEN + pix) * 32u;
                    #pragma unroll
                    for (int nt = 0; nt < 16; ++nt) {
                        const unsigned idx = base + (unsigned)(nt >> 1) * (FLEN * 32u)
                                           + (unsigned)((nt & 1) * 16 + lane15);
                        ((ushort*)out)[idx] = f2bf(acc[rt][nt][r] + bcol[nt]);
                    }
                } else {
                    float* op = (float*)out + (size_t)row * ldc + c0 + lane15;
                    #pragma unroll
                    for (int nt = 0; nt < 16; ++nt)
                        op[nt * 16] = acc[rt][nt][r] + bcol[nt];
                }
            }
        }
    }
}

// ---------------------------------------------------------------------------
// One launch, one round of 256 W-stationary blocks (1/CU, 128 KiB LDS each):
//   blocks [0,211)    : v-proj   (2805 chunks) -> v_ws bf16 scatter
//   blocks [211,226)  : (q+pos) @ Wso[:,0:256]   -> off_ws cols 0..255
//   blocks [226,241)  : (q+pos) @ Wso[:,256:512] -> off_ws cols 256..511
//   blocks [241,256)  : (q+pos) @ Waw            -> aw_ws (raw logits)
//   block  256        : bev_mask format detect -> flag (tiny tail)
// ---------------------------------------------------------------------------
__launch_bounds__(256, 1)
__global__ void fused_pre_gemm(const float* __restrict__ value,
                               const float* __restrict__ query,
                               const float* __restrict__ query_pos,
                               const float* __restrict__ Wv,  const float* __restrict__ bv,
                               const float* __restrict__ Wso, const float* __restrict__ bso,
                               const float* __restrict__ Waw, const float* __restrict__ baw,
                               const void* __restrict__ bm,
                               ushort* __restrict__ v_ws,
                               float* __restrict__ off_ws,
                               float* __restrict__ aw_ws,
                               int* __restrict__ flag) {
    __shared__ ushort sW[256 * 256];   // 128 KiB
    const int bid = blockIdx.x;
    if (bid < 211) {
        wstat_body<0>(sW, value, nullptr, Wv, 256, 0, bv, v_ws, 0, NCHUNK, bid, 211);
    } else if (bid < 226) {
        wstat_body<1>(sW, query, query_pos, Wso, 512, 0,   bso, off_ws, 512, NQCHUNK, bid - 211, 15);
    } else if (bid < 241) {
        wstat_body<1>(sW, query, query_pos, Wso, 512, 256, bso, off_ws, 512, NQCHUNK, bid - 226, 15);
    } else if (bid < 256) {
        wstat_body<1>(sW, query, query_pos, Waw, 256, 0,   baw, aw_ws, 256, NQCHUNK, bid - 241, 15);
    } else {
        // scan first 153600 B of bev_mask: bool-byte packing sets upper bytes
        // of 32-bit words; int32 0/1 values never do.
        const int t = threadIdx.x;
        const uint4* p4 = (const uint4*)bm;
        unsigned acc = 0;
        for (int i = t; i < (CAMS * NQ * DEPTH) / 16; i += 256) {
            const uint4 w = p4[i];
            acc |= w.x | w.y | w.z | w.w;
        }
        #pragma unroll
        for (int off = 32; off >= 1; off >>= 1) acc |= __shfl_xor(acc, off);
        unsigned* sred = (unsigned*)sW;
        if ((t & 63) == 0) sred[t >> 6] = acc;
        __syncthreads();
        if (t == 0) {
            const unsigned a = sred[0] | sred[1] | sred[2] | sred[3];
            flag[0] = (a & 0xFFFFFF00u) ? 1 : 0;
        }
    }
}

__launch_bounds__(256)
__global__ void gemm_out_kernel(const float* __restrict__ slots,
                                const float* __restrict__ Wout,
                                const float* __restrict__ bout,
                                const float* __restrict__ query,
                                float* __restrict__ out) {
    __shared__ ushort sA[128 * LSTRIDE];
    __shared__ ushort sB[128 * LSTRIDE];
    const int bid = blockIdx.x;
    gemm_body_out(sA, sB, slots, Wout, 256, bout, query, out, 256, NQ, bid >> 1, bid & 1);
}

// ---------------------------------------------------------------------------
// Deformable sampling — one block per (query, cam). Max TLP: the serial cam
// loop of R4 (88 µs, VGPR 68) is split across blocks; each block runs exactly
// one camera's gathers (the R4-proven 68-VGPR body) and atomically adds its
// e8-reduced partial into slots (1 atomic/thread, disjoint addresses, <=6
// adders per address over the whole grid). Inactive (q,cam) blocks exit after
// the mask read (~66%). slots is pre-zeroed via hipMemsetAsync; 1/count folds
// into the weights (distributes over the cam-sum; only fp32 add order changes).
// v layout [cam][head][pix][32ch] bf16: bilinear x/x+1 corners adjacent 64B.
// ---------------------------------------------------------------------------
__launch_bounds__(256)
__global__ void sample_kernel(const ushort* __restrict__ v,
                              const float* __restrict__ off_ws,
                              const float* __restrict__ aw_logit,
                              const float* __restrict__ rp,      // (CAMS,NQ,DEPTH,2)
                              const void* __restrict__ bm,
                              const int* __restrict__ flag,
                              float* __restrict__ slots) {
    const int q   = blockIdx.x;
    const int cam = blockIdx.y;
    const int t = threadIdx.x;
    const int h = t >> 5;
    const int e8 = (t >> 2) & 7;
    const int ch8 = (t & 3) * 8;
    const int l = e8 >> 1;
    const int ebase = h * 32 + e8 * 4;

    // speculative loads that are safe in BOTH mask formats (4B*38400 <= 153600B)
    unsigned wa[CAMS];
    #pragma unroll
    for (int c = 0; c < CAMS; ++c) wa[c] = ((const unsigned*)bm)[c * NQ + q];
    // rp load hoisted above the active check (address always valid)
    const float4 r01 = *(const float4*)(rp + (size_t)cam * (NQ * 8) + q * 8);
    const float4 r23 = *(const float4*)(rp + (size_t)cam * (NQ * 8) + q * 8 + 4);

    const int fmt = *flag;
    int am = 0, cnt = 0;
    if (fmt == 1) {         // bool bytes: 4 bytes per (cam,q)
        #pragma unroll
        for (int c = 0; c < CAMS; ++c) {
            const int a = (wa[c] != 0u);
            am |= a << c;
            cnt += a;
        }
    } else {                // int32: 16 bytes per (cam,q)
        #pragma unroll
        for (int c = 0; c < CAMS; ++c) {
            const int4 w = ((const int4*)bm)[c * NQ + q];
            const int a = ((w.x | w.y | w.z | w.w) != 0);
            am |= a << c;
            cnt += a;
        }
    }
    if (!((am >> cam) & 1)) return;     // block-uniform exit
    const float invq = 1.0f / (float)cnt;   // cnt >= 1 here

    // softmax over the 32 (l,p) logits of this (q,h): lanes differing in e8
    const float4 lg = *(const float4*)(aw_logit + (size_t)q * 256 + ebase);
    float mx = fmaxf(fmaxf(lg.x, lg.y), fmaxf(lg.z, lg.w));
    mx = fmaxf(mx, __shfl_xor(mx, 4));
    mx = fmaxf(mx, __shfl_xor(mx, 8));
    mx = fmaxf(mx, __shfl_xor(mx, 16));
    const float e0 = expf(lg.x - mx), e1 = expf(lg.y - mx);
    const float e2 = expf(lg.z - mx), e3 = expf(lg.w - mx);
    float s = e0 + e1 + e2 + e3;
    s += __shfl_xor(s, 4);
    s += __shfl_xor(s, 8);
    s += __shfl_xor(s, 16);
    const float sc = invq / s;                 // fold 1/count into the weights
    const float awv[4] = {e0 * sc, e1 * sc, e2 * sc, e3 * sc};

    const float* ofp = off_ws + (size_t)q * 512 + ebase * 2;
    const float4 o01 = *(const float4*)(ofp);
    const float4 o23 = *(const float4*)(ofp + 4);
    const float offx[4] = {o01.x, o01.z, o23.x, o23.z};
    const float offy[4] = {o01.y, o01.w, o23.y, o23.w};

    const int Wl = c_LW[l], Hl = c_LH[l], St = c_LS[l];
    const float fWl = (float)Wl, fHl = (float)Hl;

    const float rx[4] = {r01.x, r01.z, r23.x, r23.z};
    const float ry[4] = {r01.y, r01.w, r23.y, r23.w};
    const int camhF = (cam * 8 + h) * FLEN + St;

    int   addr[16];
    float wgt[16];
    #pragma unroll
    for (int j = 0; j < 4; ++j) {
        const float x = fmaf(rx[j], fWl, offx[j]) - 0.5f;
        const float y = fmaf(ry[j], fHl, offy[j]) - 0.5f;
        const float x0f = floorf(x), y0f = floorf(y);
        const int x0 = (int)x0f, y0 = (int)y0f;
        const float fx = x - x0f, fy = y - y0f;
        const float wx0 = 1.f - fx, wy0 = 1.f - fy;
        #pragma unroll
        for (int c = 0; c < 4; ++c) {
            const int cx = x0 + (c & 1);
            const int cy = y0 + (c >> 1);
            const bool valid = ((unsigned)cx < (unsigned)Wl) & ((unsigned)cy < (unsigned)Hl);
            const int pixo = valid ? (cy * Wl + cx) : 0;
            addr[j * 4 + c] = ((camhF + pixo) << 5) + ch8;
            wgt[j * 4 + c] = valid
                ? (((c & 1) ? fx : wx0) * ((c >> 1) ? fy : wy0) * awv[j])
                : 0.f;
        }
    }

    float accv[8] = {};
    #pragma unroll
    for (int i = 0; i < 16; ++i) {
        const uint4 u = *(const uint4*)(v + addr[i]);
        const float w = wgt[i];
        accv[0] = fmaf(w, bflo(u.x), accv[0]);
        accv[1] = fmaf(w, bfhi(u.x), accv[1]);
        accv[2] = fmaf(w, bflo(u.y), accv[2]);
        accv[3] = fmaf(w, bfhi(u.y), accv[3]);
        accv[4] = fmaf(w, bflo(u.z), accv[4]);
        accv[5] = fmaf(w, bfhi(u.z), accv[5]);
        accv[6] = fmaf(w, bflo(u.w), accv[6]);
        accv[7] = fmaf(w, bfhi(u.w), accv[7]);
    }

    // reduce over the 8 e8-groups (lane bits 2..4 within each 32-lane h-group)
    #pragma unroll
    for (int i = 0; i < 8; ++i) {
        accv[i] += __shfl_xor(accv[i], 4);
        accv[i] += __shfl_xor(accv[i], 8);
        accv[i] += __shfl_xor(accv[i], 16);
    }
    atomicAdd(&slots[(size_t)q * 256 + h * 32 + ch8 + e8], accv[e8]);
}

// ---------------------------------------------------------------------------
extern "C" void kernel_launch(void* const* d_in, const int* in_sizes, int n_in,
                              void* d_out, int out_size, void* d_ws, size_t ws_size,
                              hipStream_t stream) {
    const float* query     = (const float*)d_in[0];
    // d_in[1] = key (unused by reference)
    const float* value     = (const float*)d_in[2];
    const float* query_pos = (const float*)d_in[3];
    const float* refpts    = (const float*)d_in[4];
    const void*  bev_mask  = d_in[5];
    const float* Wv   = (const float*)d_in[8];
    const float* bv   = (const float*)d_in[9];
    const float* Wso  = (const float*)d_in[10];
    const float* bso  = (const float*)d_in[11];
    const float* Waw  = (const float*)d_in[12];
    const float* baw  = (const float*)d_in[13];
    const float* Wout = (const float*)d_in[14];
    const float* bout = (const float*)d_in[15];
    float* out = (float*)d_out;

    // Workspace layout
    ushort* v_ws  = (ushort*)d_ws;                       // MV*256 bf16 = 45.96 MB
    float* off_ws = (float*)(v_ws + (size_t)MV * 256);   // NQ*512 fp32
    float* aw_ws  = off_ws + (size_t)NQ * 512;           // NQ*256 (raw logits)
    float* slots  = aw_ws + (size_t)NQ * 256;            // NQ*256 (atomic accum)
    int*   flag   = (int*)(slots + (size_t)NQ * 256);    // 1 int

    // zero the atomic accumulator (graph-capture-safe; proven in R0)
    hipMemsetAsync(slots, 0, (size_t)NQ * 256 * sizeof(float), stream);

    // all projections (W-stationary, one round) + mask detect, one dispatch
    hipLaunchKernelGGL(fused_pre_gemm, dim3(257), dim3(256), 0, stream,
                       value, query, query_pos, Wv, bv, Wso, bso, Waw, baw,
                       bev_mask, v_ws, off_ws, aw_ws, flag);

    // deformable sampling: one block per (q, cam); atomic accumulation
    hipLaunchKernelGGL(sample_kernel, dim3(NQ, CAMS), dim3(256), 0, stream,
                       v_ws, off_ws, aw_ws, refpts, bev_mask, flag, slots);

    // out = slots @ Wout + bout + query   (1/count already folded into sample)
    hipLaunchKernelGGL(gemm_out_kernel, dim3(100), dim3(256), 0, stream,
                       slots, Wout, bout, query, out);
}